// Round 1
// baseline (619.694 us; speedup 1.0000x reference)
//
#include <hip/hip_runtime.h>
#include <cstdint>
#include <cmath>

#define T_TOK 1024
#define H_DIM 1024
#define E_NUM 32
#define I_DIM 512
#define IS_DIM 2048
#define NCOL_R 16384   // 32 experts * 512
#define NCOL_T 18432   // + shared 2048
#define SCALE_F 2.5f

typedef __bf16 bf16x8 __attribute__((ext_vector_type(8)));
typedef float f32x4 __attribute__((ext_vector_type(4)));

__device__ __forceinline__ unsigned short f2b(float f) {
    union { float f; uint32_t u; } v; v.f = f;
    return (unsigned short)((v.u + 0x7FFFu + ((v.u >> 16) & 1u)) >> 16);
}

// ---------------- X fp32 -> bf16 ----------------
__global__ void cvt_x_kernel(const float* __restrict__ x, unsigned short* __restrict__ xb) {
    int i = blockIdx.x * 256 + threadIdx.x;           // 262144 float4 groups
    float4 v = reinterpret_cast<const float4*>(x)[i];
    uint2 o;
    o.x = (uint32_t)f2b(v.x) | ((uint32_t)f2b(v.y) << 16);
    o.y = (uint32_t)f2b(v.z) | ((uint32_t)f2b(v.w) << 16);
    reinterpret_cast<uint2*>(xb)[i] = o;
}

// ---------------- routing ----------------
__global__ void routing_kernel(const float* __restrict__ x,
                               const float* __restrict__ gate_w,
                               const float* __restrict__ e_bias,
                               float* __restrict__ combine) {
    int t = blockIdx.x;
    int l = threadIdx.x;   // 64 threads = 1 wave
    float xv[16];
#pragma unroll
    for (int i = 0; i < 16; i++) xv[i] = x[t * H_DIM + i * 64 + l];
    __shared__ float slog[E_NUM];
    for (int e = 0; e < E_NUM; e++) {
        const float* w = gate_w + e * H_DIM;
        float s = 0.f;
#pragma unroll
        for (int i = 0; i < 16; i++) s += xv[i] * w[i * 64 + l];
#pragma unroll
        for (int off = 32; off > 0; off >>= 1) s += __shfl_down(s, off);
        if (l == 0) slog[e] = s;
    }
    __syncthreads();
    if (l == 0) {
        float scores[E_NUM], swb[E_NUM];
        for (int e = 0; e < E_NUM; e++) {
            float sg = 1.f / (1.f + expf(-slog[e]));
            scores[e] = sg;
            swb[e] = sg + e_bias[e];
        }
        // group scores: sum of top-2 within each group of 4
        float gs[8];
        for (int g = 0; g < 8; g++) {
            float a0 = swb[4*g], a1 = swb[4*g+1], a2 = swb[4*g+2], a3 = swb[4*g+3];
            float hi01 = fmaxf(a0,a1), lo01 = fminf(a0,a1);
            float hi23 = fmaxf(a2,a3), lo23 = fminf(a2,a3);
            float m1 = fmaxf(hi01, hi23);
            float m2 = fmaxf(fminf(hi01, hi23), fmaxf(lo01, lo23));
            gs[g] = m1 + m2;
        }
        bool gsel[8];
        for (int g = 0; g < 8; g++) gsel[g] = false;
        for (int it = 0; it < 4; it++) {
            int bi = 0; float bv = -1e30f;
            for (int g = 0; g < 8; g++) if (!gsel[g] && gs[g] > bv) { bv = gs[g]; bi = g; }
            gsel[bi] = true;
        }
        // candidates exactly as reference: swb * mask (masked-out -> 0.0)
        float cand[E_NUM];
        for (int e = 0; e < E_NUM; e++) cand[e] = gsel[e >> 2] ? swb[e] : 0.0f;
        bool esel[E_NUM];
        for (int e = 0; e < E_NUM; e++) esel[e] = false;
        for (int it = 0; it < 8; it++) {
            int bi = 0; float bv = -1e30f;
            for (int e = 0; e < E_NUM; e++) if (!esel[e] && cand[e] > bv) { bv = cand[e]; bi = e; }
            esel[bi] = true;
        }
        float ssum = 0.f;
        for (int e = 0; e < E_NUM; e++) if (esel[e]) ssum += scores[e];
        float inv = SCALE_F / (ssum + 1e-20f);
        for (int e = 0; e < E_NUM; e++)
            combine[t * E_NUM + e] = esel[e] ? scores[e] * inv : 0.0f;
    }
}

// ---------------- fused gate/up GEMM + SiLU + combine scale ----------------
// act[t, c] for c in [0,18432): routed expert cols (scaled by combine) then shared cols.
__global__ __launch_bounds__(256, 2)
void gateup_kernel(const unsigned short* __restrict__ xb,
                   const float* __restrict__ w_gate,
                   const float* __restrict__ w_up,
                   const float* __restrict__ ws_gate,
                   const float* __restrict__ ws_up,
                   const float* __restrict__ combine,
                   unsigned short* __restrict__ act) {
    int mb = blockIdx.x, cb = blockIdx.y;
    int row0 = mb * 128, c0 = cb * 128;
    const float *bg, *bu;
    int bstride, eidx;
    if (c0 < NCOL_R) {
        int e = c0 >> 9, ci = c0 & 511;
        bg = w_gate + (size_t)e * H_DIM * I_DIM + ci;
        bu = w_up   + (size_t)e * H_DIM * I_DIM + ci;
        bstride = I_DIM; eidx = e;
    } else {
        int ci = c0 - NCOL_R;
        bg = ws_gate + ci; bu = ws_up + ci;
        bstride = IS_DIM; eidx = -1;
    }
    __shared__ __align__(16) unsigned short lA[128*32];
    __shared__ __align__(16) unsigned short lBg[128*32];
    __shared__ __align__(16) unsigned short lBu[128*32];
    int tid = threadIdx.x, lane = tid & 63, w = tid >> 6;
    int wr = w >> 1, wc = w & 1;
    f32x4 accg[4][4], accu[4][4];
#pragma unroll
    for (int i = 0; i < 4; i++)
#pragma unroll
        for (int j = 0; j < 4; j++)
#pragma unroll
            for (int r = 0; r < 4; r++) { accg[i][j][r] = 0.f; accu[i][j][r] = 0.f; }

    int ar = tid >> 2, ak = (tid & 3) * 8;
    int bn = tid & 127, bkg = (tid >> 7) * 16;

    for (int kk = 0; kk < H_DIM / 32; kk++) {
        int k0 = kk * 32;
        __syncthreads();
        // A stage: bf16 [m][k], rows 0..127
        *reinterpret_cast<uint4*>(&lA[ar*32 + ak]) =
            *reinterpret_cast<const uint4*>(xb + (size_t)(row0 + ar) * H_DIM + k0 + ak);
        *reinterpret_cast<uint4*>(&lA[(ar+64)*32 + ak]) =
            *reinterpret_cast<const uint4*>(xb + (size_t)(row0 + ar + 64) * H_DIM + k0 + ak);
        // B stage with fp32->bf16 + transpose into [n][k]
#pragma unroll
        for (int p = 0; p < 4; p++) {
            int kb = bkg + p * 4;
            const float* pg = bg + (size_t)(k0 + kb) * bstride + bn;
            uint2 dg;
            dg.x = (uint32_t)f2b(pg[0])         | ((uint32_t)f2b(pg[bstride])   << 16);
            dg.y = (uint32_t)f2b(pg[2*bstride]) | ((uint32_t)f2b(pg[3*bstride]) << 16);
            *reinterpret_cast<uint2*>(&lBg[bn*32 + kb]) = dg;
            const float* pu = bu + (size_t)(k0 + kb) * bstride + bn;
            uint2 du;
            du.x = (uint32_t)f2b(pu[0])         | ((uint32_t)f2b(pu[bstride])   << 16);
            du.y = (uint32_t)f2b(pu[2*bstride]) | ((uint32_t)f2b(pu[3*bstride]) << 16);
            *reinterpret_cast<uint2*>(&lBu[bn*32 + kb]) = du;
        }
        __syncthreads();
        bf16x8 af[4], bgf[4], buf2[4];
#pragma unroll
        for (int mi = 0; mi < 4; mi++)
            af[mi] = *reinterpret_cast<const bf16x8*>(&lA[(wr*64 + mi*16 + (lane & 15))*32 + (lane >> 4)*8]);
#pragma unroll
        for (int ni = 0; ni < 4; ni++) {
            int nn = (wc*64 + ni*16 + (lane & 15))*32 + (lane >> 4)*8;
            bgf[ni]  = *reinterpret_cast<const bf16x8*>(&lBg[nn]);
            buf2[ni] = *reinterpret_cast<const bf16x8*>(&lBu[nn]);
        }
#pragma unroll
        for (int mi = 0; mi < 4; mi++)
#pragma unroll
            for (int ni = 0; ni < 4; ni++) {
                accg[mi][ni] = __builtin_amdgcn_mfma_f32_16x16x32_bf16(af[mi], bgf[ni],  accg[mi][ni], 0, 0, 0);
                accu[mi][ni] = __builtin_amdgcn_mfma_f32_16x16x32_bf16(af[mi], buf2[ni], accu[mi][ni], 0, 0, 0);
            }
    }
    // epilogue: silu(g)*u * combine -> bf16 act
    int q = lane >> 4, cl = lane & 15;
#pragma unroll
    for (int mi = 0; mi < 4; mi++) {
#pragma unroll
        for (int ni = 0; ni < 4; ni++) {
            int colg = c0 + wc*64 + ni*16 + cl;
#pragma unroll
            for (int r = 0; r < 4; r++) {
                int row = row0 + wr*64 + mi*16 + q*4 + r;
                float g = accg[mi][ni][r], u = accu[mi][ni][r];
                float a = g / (1.f + expf(-g)) * u;
                float s = (eidx >= 0) ? combine[row * E_NUM + eidx] : 1.0f;
                act[(size_t)row * NCOL_T + colg] = f2b(a * s);
            }
        }
    }
}

// ---------------- down GEMM: out_partial = act @ [w_down ; ws_down], split-K ----------------
__global__ __launch_bounds__(256, 2)
void down_kernel(const unsigned short* __restrict__ act,
                 const float* __restrict__ w_down,
                 const float* __restrict__ ws_down,
                 float* __restrict__ partials) {
    int mb = blockIdx.x, nb = blockIdx.y, ks = blockIdx.z;
    int row0 = mb * 128, n0 = nb * 128;
    __shared__ __align__(16) unsigned short lA[128*32];
    __shared__ __align__(16) unsigned short lB[128*32];
    int tid = threadIdx.x, lane = tid & 63, w = tid >> 6;
    int wr = w >> 1, wc = w & 1;
    f32x4 acc[4][4];
#pragma unroll
    for (int i = 0; i < 4; i++)
#pragma unroll
        for (int j = 0; j < 4; j++)
#pragma unroll
            for (int r = 0; r < 4; r++) acc[i][j][r] = 0.f;

    int ar = tid >> 2, ak = (tid & 3) * 8;
    int bn = tid & 127, bkg = (tid >> 7) * 16;

    for (int kk = 0; kk < 144; kk++) {
        int k0 = ks * 4608 + kk * 32;
        const float* bb = (k0 < NCOL_R) ? (w_down + (size_t)k0 * H_DIM)
                                        : (ws_down + (size_t)(k0 - NCOL_R) * H_DIM);
        __syncthreads();
        *reinterpret_cast<uint4*>(&lA[ar*32 + ak]) =
            *reinterpret_cast<const uint4*>(act + (size_t)(row0 + ar) * NCOL_T + k0 + ak);
        *reinterpret_cast<uint4*>(&lA[(ar+64)*32 + ak]) =
            *reinterpret_cast<const uint4*>(act + (size_t)(row0 + ar + 64) * NCOL_T + k0 + ak);
#pragma unroll
        for (int p = 0; p < 4; p++) {
            int kb = bkg + p * 4;
            const float* pb = bb + (size_t)kb * H_DIM + n0 + bn;
            uint2 d;
            d.x = (uint32_t)f2b(pb[0])       | ((uint32_t)f2b(pb[H_DIM])   << 16);
            d.y = (uint32_t)f2b(pb[2*H_DIM]) | ((uint32_t)f2b(pb[3*H_DIM]) << 16);
            *reinterpret_cast<uint2*>(&lB[bn*32 + kb]) = d;
        }
        __syncthreads();
        bf16x8 af[4], bf[4];
#pragma unroll
        for (int mi = 0; mi < 4; mi++)
            af[mi] = *reinterpret_cast<const bf16x8*>(&lA[(wr*64 + mi*16 + (lane & 15))*32 + (lane >> 4)*8]);
#pragma unroll
        for (int ni = 0; ni < 4; ni++)
            bf[ni] = *reinterpret_cast<const bf16x8*>(&lB[(wc*64 + ni*16 + (lane & 15))*32 + (lane >> 4)*8]);
#pragma unroll
        for (int mi = 0; mi < 4; mi++)
#pragma unroll
            for (int ni = 0; ni < 4; ni++)
                acc[mi][ni] = __builtin_amdgcn_mfma_f32_16x16x32_bf16(af[mi], bf[ni], acc[mi][ni], 0, 0, 0);
    }
    float* pout = partials + ((size_t)ks << 20);
    int q = lane >> 4, cl = lane & 15;
#pragma unroll
    for (int mi = 0; mi < 4; mi++) {
#pragma unroll
        for (int ni = 0; ni < 4; ni++) {
            int col = n0 + wc*64 + ni*16 + cl;
#pragma unroll
            for (int r = 0; r < 4; r++) {
                int row = row0 + wr*64 + mi*16 + q*4 + r;
                pout[(size_t)row * H_DIM + col] = acc[mi][ni][r];
            }
        }
    }
}

// ---------------- reduce split-K partials ----------------
__global__ void reduce_kernel(const float* __restrict__ p, float* __restrict__ out) {
    int i = blockIdx.x * 256 + threadIdx.x;  // over 262144 float4
    float4 a = reinterpret_cast<const float4*>(p)[i];
    float4 b = reinterpret_cast<const float4*>(p + (size_t)1048576)[i];
    float4 c = reinterpret_cast<const float4*>(p + (size_t)2097152)[i];
    float4 d = reinterpret_cast<const float4*>(p + (size_t)3145728)[i];
    float4 o;
    o.x = a.x + b.x + c.x + d.x;
    o.y = a.y + b.y + c.y + d.y;
    o.z = a.z + b.z + c.z + d.z;
    o.w = a.w + b.w + c.w + d.w;
    reinterpret_cast<float4*>(out)[i] = o;
}

extern "C" void kernel_launch(void* const* d_in, const int* in_sizes, int n_in,
                              void* d_out, int out_size, void* d_ws, size_t ws_size,
                              hipStream_t stream) {
    const float* x       = (const float*)d_in[0];
    const float* gate_w  = (const float*)d_in[1];
    const float* e_bias  = (const float*)d_in[2];
    const float* w_gate  = (const float*)d_in[3];
    const float* w_up    = (const float*)d_in[4];
    const float* w_down  = (const float*)d_in[5];
    const float* ws_gate = (const float*)d_in[6];
    const float* ws_up   = (const float*)d_in[7];
    const float* ws_down = (const float*)d_in[8];
    float* out = (float*)d_out;

    char* ws = (char*)d_ws;
    float* combine        = (float*)ws;                              // 131072 B
    unsigned short* xb    = (unsigned short*)(ws + 131072);          // 2 MB
    unsigned short* act   = (unsigned short*)(ws + 131072 + 2097152);            // 36 MB
    float* partials       = (float*)(ws + 131072 + 2097152 + 37748736);          // 16 MB

    cvt_x_kernel<<<1024, 256, 0, stream>>>(x, xb);
    routing_kernel<<<1024, 64, 0, stream>>>(x, gate_w, e_bias, combine);
    gateup_kernel<<<dim3(8, 144), 256, 0, stream>>>(xb, w_gate, w_up, ws_gate, ws_up, combine, act);
    down_kernel<<<dim3(8, 8, 4), 256, 0, stream>>>(act, w_down, ws_down, partials);
    reduce_kernel<<<1024, 256, 0, stream>>>(partials, out);
}

// Round 2
// 500.368 us; speedup vs baseline: 1.2385x; 1.2385x over previous
//
#include <hip/hip_runtime.h>
#include <cstdint>
#include <cmath>

#define T_TOK 1024
#define H_DIM 1024
#define E_NUM 32
#define I_DIM 512
#define IS_DIM 2048
#define NCOL_R 16384   // 32 experts * 512
#define NCOL_T 18432   // + shared 2048
#define SCALE_F 2.5f

typedef __bf16 bf16x8 __attribute__((ext_vector_type(8)));
typedef float f32x4 __attribute__((ext_vector_type(4)));

typedef __attribute__((address_space(3))) unsigned int lds_u32_t;
typedef __attribute__((address_space(1))) const unsigned int glb_u32_t;

__device__ __forceinline__ unsigned short f2b(float f) {
    union { float f; uint32_t u; } v; v.f = f;
    return (unsigned short)((v.u + 0x7FFFu + ((v.u >> 16) & 1u)) >> 16);
}

// async global->LDS, 16B per lane. LDS base must be wave-uniform; HW writes
// ldsbase + lane*16. Completion is covered by the vmcnt(0) drain the compiler
// emits before s_barrier (__syncthreads).
__device__ __forceinline__ void gll16(const unsigned short* g, unsigned short* l) {
    __builtin_amdgcn_global_load_lds((glb_u32_t*)g, (lds_u32_t*)l, 16, 0, 0);
}

// ---------------- X fp32 -> bf16 ----------------
__global__ void cvt_x_kernel(const float* __restrict__ x, unsigned short* __restrict__ xb) {
    int i = blockIdx.x * 256 + threadIdx.x;           // 262144 float4 groups
    float4 v = reinterpret_cast<const float4*>(x)[i];
    uint2 o;
    o.x = (uint32_t)f2b(v.x) | ((uint32_t)f2b(v.y) << 16);
    o.y = (uint32_t)f2b(v.z) | ((uint32_t)f2b(v.w) << 16);
    reinterpret_cast<uint2*>(xb)[i] = o;
}

// ---------------- weight fp32 [R][C] -> bf16 transposed dst[c][r] ----------------
// dst element (c,r) at: dst + dst_base + b*dst_batch + (c0+c)*DS + r
__global__ __launch_bounds__(256)
void tcvt_kernel(const float* __restrict__ src, unsigned short* __restrict__ dst,
                 int C, int DS, size_t src_batch, size_t dst_batch, size_t dst_base) {
    int b = blockIdx.z;
    int r0 = blockIdx.x * 64, c0 = blockIdx.y * 64;
    const float* s = src + (size_t)b * src_batch;
    __shared__ float tile[64][68];
    int t = threadIdx.x;
    int lr = t >> 4, lc4 = (t & 15) * 4;
#pragma unroll
    for (int p = 0; p < 4; p++) {
        float4 v = *reinterpret_cast<const float4*>(s + (size_t)(r0 + lr + p * 16) * C + c0 + lc4);
        *reinterpret_cast<float4*>(&tile[lr + p * 16][lc4]) = v;
    }
    __syncthreads();
    int oc = t >> 2, orr = (t & 3) * 16;
    uint32_t o[8];
#pragma unroll
    for (int j = 0; j < 8; j++) {
        o[j] = (uint32_t)f2b(tile[orr + 2 * j][oc]) | ((uint32_t)f2b(tile[orr + 2 * j + 1][oc]) << 16);
    }
    unsigned short* dp = dst + dst_base + (size_t)b * dst_batch + (size_t)(c0 + oc) * DS + r0 + orr;
    uint4 u0; u0.x = o[0]; u0.y = o[1]; u0.z = o[2]; u0.w = o[3];
    uint4 u1; u1.x = o[4]; u1.y = o[5]; u1.z = o[6]; u1.w = o[7];
    *reinterpret_cast<uint4*>(dp) = u0;
    *reinterpret_cast<uint4*>(dp + 8) = u1;
}

// ---------------- routing ----------------
__global__ void routing_kernel(const float* __restrict__ x,
                               const float* __restrict__ gate_w,
                               const float* __restrict__ e_bias,
                               float* __restrict__ combine) {
    int t = blockIdx.x;
    int l = threadIdx.x;   // 64 threads = 1 wave
    float xv[16];
#pragma unroll
    for (int i = 0; i < 16; i++) xv[i] = x[t * H_DIM + i * 64 + l];
    __shared__ float slog[E_NUM];
    for (int e = 0; e < E_NUM; e++) {
        const float* w = gate_w + e * H_DIM;
        float s = 0.f;
#pragma unroll
        for (int i = 0; i < 16; i++) s += xv[i] * w[i * 64 + l];
#pragma unroll
        for (int off = 32; off > 0; off >>= 1) s += __shfl_down(s, off);
        if (l == 0) slog[e] = s;
    }
    __syncthreads();
    if (l == 0) {
        float scores[E_NUM], swb[E_NUM];
        for (int e = 0; e < E_NUM; e++) {
            float sg = 1.f / (1.f + expf(-slog[e]));
            scores[e] = sg;
            swb[e] = sg + e_bias[e];
        }
        float gs[8];
        for (int g = 0; g < 8; g++) {
            float a0 = swb[4*g], a1 = swb[4*g+1], a2 = swb[4*g+2], a3 = swb[4*g+3];
            float hi01 = fmaxf(a0,a1), lo01 = fminf(a0,a1);
            float hi23 = fmaxf(a2,a3), lo23 = fminf(a2,a3);
            float m1 = fmaxf(hi01, hi23);
            float m2 = fmaxf(fminf(hi01, hi23), fmaxf(lo01, lo23));
            gs[g] = m1 + m2;
        }
        bool gsel[8];
        for (int g = 0; g < 8; g++) gsel[g] = false;
        for (int it = 0; it < 4; it++) {
            int bi = 0; float bv = -1e30f;
            for (int g = 0; g < 8; g++) if (!gsel[g] && gs[g] > bv) { bv = gs[g]; bi = g; }
            gsel[bi] = true;
        }
        float cand[E_NUM];
        for (int e = 0; e < E_NUM; e++) cand[e] = gsel[e >> 2] ? swb[e] : 0.0f;
        bool esel[E_NUM];
        for (int e = 0; e < E_NUM; e++) esel[e] = false;
        for (int it = 0; it < 8; it++) {
            int bi = 0; float bv = -1e30f;
            for (int e = 0; e < E_NUM; e++) if (!esel[e] && cand[e] > bv) { bv = cand[e]; bi = e; }
            esel[bi] = true;
        }
        float ssum = 0.f;
        for (int e = 0; e < E_NUM; e++) if (esel[e]) ssum += scores[e];
        float inv = SCALE_F / (ssum + 1e-20f);
        for (int e = 0; e < E_NUM; e++)
            combine[t * E_NUM + e] = esel[e] ? scores[e] * inv : 0.0f;
    }
}

// ================= FAST PATH: bf16 weights, global_load_lds staging =================

// gateup: act[t, c] = silu(x@BG^T) * (x@BU^T) * combine, c in [0,18432)
__global__ __launch_bounds__(256, 2)
void gateup_f(const unsigned short* __restrict__ xb,
              const unsigned short* __restrict__ BG,
              const unsigned short* __restrict__ BU,
              const float* __restrict__ combine,
              unsigned short* __restrict__ act) {
    int mb = blockIdx.x, cb = blockIdx.y;
    int row0 = mb * 128, c0 = cb * 128;
    int eidx = (c0 < NCOL_R) ? (c0 >> 9) : -1;
    __shared__ __align__(16) unsigned short lA[128*32];
    __shared__ __align__(16) unsigned short lBg[128*32];
    __shared__ __align__(16) unsigned short lBu[128*32];
    int tid = threadIdx.x, lane = tid & 63, w = tid >> 6;
    int wr = w >> 1, wc = w & 1;
    f32x4 accg[4][4], accu[4][4];
#pragma unroll
    for (int i = 0; i < 4; i++)
#pragma unroll
        for (int j = 0; j < 4; j++)
#pragma unroll
            for (int r = 0; r < 4; r++) { accg[i][j][r] = 0.f; accu[i][j][r] = 0.f; }

    int srow = w * 32 + (lane >> 2);        // this lane's staging row (p=0 half)
    int schunk = (lane & 3) * 8;
    const unsigned short* gA0 = xb + (size_t)(row0 + srow) * H_DIM + schunk;
    const unsigned short* gG0 = BG + (size_t)(c0 + srow) * H_DIM + schunk;
    const unsigned short* gU0 = BU + (size_t)(c0 + srow) * H_DIM + schunk;
    unsigned short* lA0 = &lA[(w * 32) * 32];
    unsigned short* lG0 = &lBg[(w * 32) * 32];
    unsigned short* lU0 = &lBu[(w * 32) * 32];

    for (int kk = 0; kk < H_DIM / 32; kk++) {
        int k0 = kk * 32;
        __syncthreads();
        gll16(gA0 + k0, lA0);
        gll16(gA0 + 16 * H_DIM + k0, lA0 + 16 * 32);
        gll16(gG0 + k0, lG0);
        gll16(gG0 + 16 * H_DIM + k0, lG0 + 16 * 32);
        gll16(gU0 + k0, lU0);
        gll16(gU0 + 16 * H_DIM + k0, lU0 + 16 * 32);
        __syncthreads();
        bf16x8 af[4], bgf[4], buf2[4];
#pragma unroll
        for (int mi = 0; mi < 4; mi++)
            af[mi] = *reinterpret_cast<const bf16x8*>(&lA[(wr*64 + mi*16 + (lane & 15))*32 + (lane >> 4)*8]);
#pragma unroll
        for (int ni = 0; ni < 4; ni++) {
            int nn = (wc*64 + ni*16 + (lane & 15))*32 + (lane >> 4)*8;
            bgf[ni]  = *reinterpret_cast<const bf16x8*>(&lBg[nn]);
            buf2[ni] = *reinterpret_cast<const bf16x8*>(&lBu[nn]);
        }
#pragma unroll
        for (int mi = 0; mi < 4; mi++)
#pragma unroll
            for (int ni = 0; ni < 4; ni++) {
                accg[mi][ni] = __builtin_amdgcn_mfma_f32_16x16x32_bf16(af[mi], bgf[ni],  accg[mi][ni], 0, 0, 0);
                accu[mi][ni] = __builtin_amdgcn_mfma_f32_16x16x32_bf16(af[mi], buf2[ni], accu[mi][ni], 0, 0, 0);
            }
    }
    int q = lane >> 4, cl = lane & 15;
#pragma unroll
    for (int mi = 0; mi < 4; mi++) {
#pragma unroll
        for (int ni = 0; ni < 4; ni++) {
            int colg = c0 + wc*64 + ni*16 + cl;
#pragma unroll
            for (int r = 0; r < 4; r++) {
                int row = row0 + wr*64 + mi*16 + q*4 + r;
                float g = accg[mi][ni][r], u = accu[mi][ni][r];
                float a = g / (1.f + expf(-g)) * u;
                float s = (eidx >= 0) ? combine[row * E_NUM + eidx] : 1.0f;
                act[(size_t)row * NCOL_T + colg] = f2b(a * s);
            }
        }
    }
}

// down: partials[ks] = act @ BD^T over K-chunk, split-K=8
__global__ __launch_bounds__(256, 2)
void down_f(const unsigned short* __restrict__ act,
            const unsigned short* __restrict__ BD,
            float* __restrict__ partials) {
    int mb = blockIdx.x, nb = blockIdx.y, ks = blockIdx.z;
    int row0 = mb * 128, n0 = nb * 128;
    __shared__ __align__(16) unsigned short lA[128*32];
    __shared__ __align__(16) unsigned short lB[128*32];
    int tid = threadIdx.x, lane = tid & 63, w = tid >> 6;
    int wr = w >> 1, wc = w & 1;
    f32x4 acc[4][4];
#pragma unroll
    for (int i = 0; i < 4; i++)
#pragma unroll
        for (int j = 0; j < 4; j++)
#pragma unroll
            for (int r = 0; r < 4; r++) acc[i][j][r] = 0.f;

    int srow = w * 32 + (lane >> 2);
    int schunk = (lane & 3) * 8;
    const unsigned short* gA0 = act + (size_t)(row0 + srow) * NCOL_T + schunk;
    const unsigned short* gB0 = BD  + (size_t)(n0 + srow) * NCOL_T + schunk;
    unsigned short* lA0 = &lA[(w * 32) * 32];
    unsigned short* lB0 = &lB[(w * 32) * 32];

    for (int kk = 0; kk < 72; kk++) {          // 8 * 2304 = 18432
        int k0 = ks * 2304 + kk * 32;
        __syncthreads();
        gll16(gA0 + k0, lA0);
        gll16(gA0 + 16 * NCOL_T + k0, lA0 + 16 * 32);
        gll16(gB0 + k0, lB0);
        gll16(gB0 + 16 * NCOL_T + k0, lB0 + 16 * 32);
        __syncthreads();
        bf16x8 af[4], bf[4];
#pragma unroll
        for (int mi = 0; mi < 4; mi++)
            af[mi] = *reinterpret_cast<const bf16x8*>(&lA[(wr*64 + mi*16 + (lane & 15))*32 + (lane >> 4)*8]);
#pragma unroll
        for (int ni = 0; ni < 4; ni++)
            bf[ni] = *reinterpret_cast<const bf16x8*>(&lB[(wc*64 + ni*16 + (lane & 15))*32 + (lane >> 4)*8]);
#pragma unroll
        for (int mi = 0; mi < 4; mi++)
#pragma unroll
            for (int ni = 0; ni < 4; ni++)
                acc[mi][ni] = __builtin_amdgcn_mfma_f32_16x16x32_bf16(af[mi], bf[ni], acc[mi][ni], 0, 0, 0);
    }
    float* pout = partials + ((size_t)ks << 20);
    int q = lane >> 4, cl = lane & 15;
#pragma unroll
    for (int mi = 0; mi < 4; mi++) {
#pragma unroll
        for (int ni = 0; ni < 4; ni++) {
            int col = n0 + wc*64 + ni*16 + cl;
#pragma unroll
            for (int r = 0; r < 4; r++) {
                int row = row0 + wr*64 + mi*16 + q*4 + r;
                pout[(size_t)row * H_DIM + col] = acc[mi][ni][r];
            }
        }
    }
}

__global__ void reduce8_kernel(const float* __restrict__ p, float* __restrict__ out) {
    int i = blockIdx.x * 256 + threadIdx.x;  // 262144 float4
    float4 o = reinterpret_cast<const float4*>(p)[i];
#pragma unroll
    for (int s = 1; s < 8; s++) {
        float4 v = reinterpret_cast<const float4*>(p + (size_t)s * 1048576)[i];
        o.x += v.x; o.y += v.y; o.z += v.z; o.w += v.w;
    }
    reinterpret_cast<float4*>(out)[i] = o;
}

// ================= FALLBACK PATH (round-1 kernels, small ws) =================

__global__ __launch_bounds__(256, 2)
void gateup_kernel(const unsigned short* __restrict__ xb,
                   const float* __restrict__ w_gate,
                   const float* __restrict__ w_up,
                   const float* __restrict__ ws_gate,
                   const float* __restrict__ ws_up,
                   const float* __restrict__ combine,
                   unsigned short* __restrict__ act) {
    int mb = blockIdx.x, cb = blockIdx.y;
    int row0 = mb * 128, c0 = cb * 128;
    const float *bg, *bu;
    int bstride, eidx;
    if (c0 < NCOL_R) {
        int e = c0 >> 9, ci = c0 & 511;
        bg = w_gate + (size_t)e * H_DIM * I_DIM + ci;
        bu = w_up   + (size_t)e * H_DIM * I_DIM + ci;
        bstride = I_DIM; eidx = e;
    } else {
        int ci = c0 - NCOL_R;
        bg = ws_gate + ci; bu = ws_up + ci;
        bstride = IS_DIM; eidx = -1;
    }
    __shared__ __align__(16) unsigned short lA[128*32];
    __shared__ __align__(16) unsigned short lBg[128*32];
    __shared__ __align__(16) unsigned short lBu[128*32];
    int tid = threadIdx.x, lane = tid & 63, w = tid >> 6;
    int wr = w >> 1, wc = w & 1;
    f32x4 accg[4][4], accu[4][4];
#pragma unroll
    for (int i = 0; i < 4; i++)
#pragma unroll
        for (int j = 0; j < 4; j++)
#pragma unroll
            for (int r = 0; r < 4; r++) { accg[i][j][r] = 0.f; accu[i][j][r] = 0.f; }
    int ar = tid >> 2, ak = (tid & 3) * 8;
    int bn = tid & 127, bkg = (tid >> 7) * 16;
    for (int kk = 0; kk < H_DIM / 32; kk++) {
        int k0 = kk * 32;
        __syncthreads();
        *reinterpret_cast<uint4*>(&lA[ar*32 + ak]) =
            *reinterpret_cast<const uint4*>(xb + (size_t)(row0 + ar) * H_DIM + k0 + ak);
        *reinterpret_cast<uint4*>(&lA[(ar+64)*32 + ak]) =
            *reinterpret_cast<const uint4*>(xb + (size_t)(row0 + ar + 64) * H_DIM + k0 + ak);
#pragma unroll
        for (int p = 0; p < 4; p++) {
            int kb = bkg + p * 4;
            const float* pg = bg + (size_t)(k0 + kb) * bstride + bn;
            uint2 dg;
            dg.x = (uint32_t)f2b(pg[0])         | ((uint32_t)f2b(pg[bstride])   << 16);
            dg.y = (uint32_t)f2b(pg[2*bstride]) | ((uint32_t)f2b(pg[3*bstride]) << 16);
            *reinterpret_cast<uint2*>(&lBg[bn*32 + kb]) = dg;
            const float* pu = bu + (size_t)(k0 + kb) * bstride + bn;
            uint2 du;
            du.x = (uint32_t)f2b(pu[0])         | ((uint32_t)f2b(pu[bstride])   << 16);
            du.y = (uint32_t)f2b(pu[2*bstride]) | ((uint32_t)f2b(pu[3*bstride]) << 16);
            *reinterpret_cast<uint2*>(&lBu[bn*32 + kb]) = du;
        }
        __syncthreads();
        bf16x8 af[4], bgf[4], buf2[4];
#pragma unroll
        for (int mi = 0; mi < 4; mi++)
            af[mi] = *reinterpret_cast<const bf16x8*>(&lA[(wr*64 + mi*16 + (lane & 15))*32 + (lane >> 4)*8]);
#pragma unroll
        for (int ni = 0; ni < 4; ni++) {
            int nn = (wc*64 + ni*16 + (lane & 15))*32 + (lane >> 4)*8;
            bgf[ni]  = *reinterpret_cast<const bf16x8*>(&lBg[nn]);
            buf2[ni] = *reinterpret_cast<const bf16x8*>(&lBu[nn]);
        }
#pragma unroll
        for (int mi = 0; mi < 4; mi++)
#pragma unroll
            for (int ni = 0; ni < 4; ni++) {
                accg[mi][ni] = __builtin_amdgcn_mfma_f32_16x16x32_bf16(af[mi], bgf[ni],  accg[mi][ni], 0, 0, 0);
                accu[mi][ni] = __builtin_amdgcn_mfma_f32_16x16x32_bf16(af[mi], buf2[ni], accu[mi][ni], 0, 0, 0);
            }
    }
    int q = lane >> 4, cl = lane & 15;
#pragma unroll
    for (int mi = 0; mi < 4; mi++) {
#pragma unroll
        for (int ni = 0; ni < 4; ni++) {
            int colg = c0 + wc*64 + ni*16 + cl;
#pragma unroll
            for (int r = 0; r < 4; r++) {
                int row = row0 + wr*64 + mi*16 + q*4 + r;
                float g = accg[mi][ni][r], u = accu[mi][ni][r];
                float a = g / (1.f + expf(-g)) * u;
                float s = (eidx >= 0) ? combine[row * E_NUM + eidx] : 1.0f;
                act[(size_t)row * NCOL_T + colg] = f2b(a * s);
            }
        }
    }
}

__global__ __launch_bounds__(256, 2)
void down_kernel(const unsigned short* __restrict__ act,
                 const float* __restrict__ w_down,
                 const float* __restrict__ ws_down,
                 float* __restrict__ partials) {
    int mb = blockIdx.x, nb = blockIdx.y, ks = blockIdx.z;
    int row0 = mb * 128, n0 = nb * 128;
    __shared__ __align__(16) unsigned short lA[128*32];
    __shared__ __align__(16) unsigned short lB[128*32];
    int tid = threadIdx.x, lane = tid & 63, w = tid >> 6;
    int wr = w >> 1, wc = w & 1;
    f32x4 acc[4][4];
#pragma unroll
    for (int i = 0; i < 4; i++)
#pragma unroll
        for (int j = 0; j < 4; j++)
#pragma unroll
            for (int r = 0; r < 4; r++) acc[i][j][r] = 0.f;
    int ar = tid >> 2, ak = (tid & 3) * 8;
    int bn = tid & 127, bkg = (tid >> 7) * 16;
    for (int kk = 0; kk < 144; kk++) {
        int k0 = ks * 4608 + kk * 32;
        const float* bb = (k0 < NCOL_R) ? (w_down + (size_t)k0 * H_DIM)
                                        : (ws_down + (size_t)(k0 - NCOL_R) * H_DIM);
        __syncthreads();
        *reinterpret_cast<uint4*>(&lA[ar*32 + ak]) =
            *reinterpret_cast<const uint4*>(act + (size_t)(row0 + ar) * NCOL_T + k0 + ak);
        *reinterpret_cast<uint4*>(&lA[(ar+64)*32 + ak]) =
            *reinterpret_cast<const uint4*>(act + (size_t)(row0 + ar + 64) * NCOL_T + k0 + ak);
#pragma unroll
        for (int p = 0; p < 4; p++) {
            int kb = bkg + p * 4;
            const float* pb = bb + (size_t)kb * H_DIM + n0 + bn;
            uint2 d;
            d.x = (uint32_t)f2b(pb[0])       | ((uint32_t)f2b(pb[H_DIM])   << 16);
            d.y = (uint32_t)f2b(pb[2*H_DIM]) | ((uint32_t)f2b(pb[3*H_DIM]) << 16);
            *reinterpret_cast<uint2*>(&lB[bn*32 + kb]) = d;
        }
        __syncthreads();
        bf16x8 af[4], bf[4];
#pragma unroll
        for (int mi = 0; mi < 4; mi++)
            af[mi] = *reinterpret_cast<const bf16x8*>(&lA[(wr*64 + mi*16 + (lane & 15))*32 + (lane >> 4)*8]);
#pragma unroll
        for (int ni = 0; ni < 4; ni++)
            bf[ni] = *reinterpret_cast<const bf16x8*>(&lB[(wc*64 + ni*16 + (lane & 15))*32 + (lane >> 4)*8]);
#pragma unroll
        for (int mi = 0; mi < 4; mi++)
#pragma unroll
            for (int ni = 0; ni < 4; ni++)
                acc[mi][ni] = __builtin_amdgcn_mfma_f32_16x16x32_bf16(af[mi], bf[ni], acc[mi][ni], 0, 0, 0);
    }
    float* pout = partials + ((size_t)ks << 20);
    int q = lane >> 4, cl = lane & 15;
#pragma unroll
    for (int mi = 0; mi < 4; mi++) {
#pragma unroll
        for (int ni = 0; ni < 4; ni++) {
            int col = n0 + wc*64 + ni*16 + cl;
#pragma unroll
            for (int r = 0; r < 4; r++) {
                int row = row0 + wr*64 + mi*16 + q*4 + r;
                pout[(size_t)row * H_DIM + col] = acc[mi][ni][r];
            }
        }
    }
}

__global__ void reduce_kernel(const float* __restrict__ p, float* __restrict__ out) {
    int i = blockIdx.x * 256 + threadIdx.x;
    float4 a = reinterpret_cast<const float4*>(p)[i];
    float4 b = reinterpret_cast<const float4*>(p + (size_t)1048576)[i];
    float4 c = reinterpret_cast<const float4*>(p + (size_t)2097152)[i];
    float4 d = reinterpret_cast<const float4*>(p + (size_t)3145728)[i];
    float4 o;
    o.x = a.x + b.x + c.x + d.x;
    o.y = a.y + b.y + c.y + d.y;
    o.z = a.z + b.z + c.z + d.z;
    o.w = a.w + b.w + c.w + d.w;
    reinterpret_cast<float4*>(out)[i] = o;
}

extern "C" void kernel_launch(void* const* d_in, const int* in_sizes, int n_in,
                              void* d_out, int out_size, void* d_ws, size_t ws_size,
                              hipStream_t stream) {
    const float* x       = (const float*)d_in[0];
    const float* gate_w  = (const float*)d_in[1];
    const float* e_bias  = (const float*)d_in[2];
    const float* w_gate  = (const float*)d_in[3];
    const float* w_up    = (const float*)d_in[4];
    const float* w_down  = (const float*)d_in[5];
    const float* ws_gate = (const float*)d_in[6];
    const float* ws_up   = (const float*)d_in[7];
    const float* ws_down = (const float*)d_in[8];
    float* out = (float*)d_out;

    char* ws = (char*)d_ws;
    // ws_size is constant across calls -> branching on it is graph-capture-safe.
    bool fast = ws_size >= 170000384ull;

    if (fast) {
        float* combine     = (float*)(ws);                    // 131072 B
        unsigned short* xb = (unsigned short*)(ws + 131072);  // 2 MB
        unsigned short* act= (unsigned short*)(ws + 2228224); // 36 MB
        unsigned short* BG = (unsigned short*)(ws + 39976960);   // 36 MB
        unsigned short* BU = (unsigned short*)(ws + 77725696);   // 36 MB
        unsigned short* BD = (unsigned short*)(ws + 115474432);  // 36 MB
        float* partials    = (float*)(ws + 39976960);  // aliases BG (dead after gateup)

        cvt_x_kernel<<<1024, 256, 0, stream>>>(x, xb);
        routing_kernel<<<1024, 64, 0, stream>>>(x, gate_w, e_bias, combine);
        // w_gate [32][1024h][512i] -> BG[e*512+i][h]
        tcvt_kernel<<<dim3(16, 8, 32), 256, 0, stream>>>(w_gate, BG, 512, 1024, 524288, 524288, 0);
        tcvt_kernel<<<dim3(16, 8, 32), 256, 0, stream>>>(w_up,   BU, 512, 1024, 524288, 524288, 0);
        // ws_gate [1024h][2048i] -> BG[16384+i][h]
        tcvt_kernel<<<dim3(16, 32, 1), 256, 0, stream>>>(ws_gate, BG, 2048, 1024, 0, 0, 16777216);
        tcvt_kernel<<<dim3(16, 32, 1), 256, 0, stream>>>(ws_up,   BU, 2048, 1024, 0, 0, 16777216);
        // w_down [32][512i][1024h] -> BD[h][e*512+i]
        tcvt_kernel<<<dim3(8, 16, 32), 256, 0, stream>>>(w_down, BD, 1024, 18432, 524288, 512, 0);
        // ws_down [2048is][1024h] -> BD[h][16384+is]
        tcvt_kernel<<<dim3(32, 16, 1), 256, 0, stream>>>(ws_down, BD, 1024, 18432, 0, 0, 16384);

        gateup_f<<<dim3(8, 144), 256, 0, stream>>>(xb, BG, BU, combine, act);
        down_f<<<dim3(8, 8, 8), 256, 0, stream>>>(act, BD, partials);
        reduce8_kernel<<<1024, 256, 0, stream>>>(partials, out);
    } else {
        float* combine     = (float*)(ws);
        unsigned short* xb = (unsigned short*)(ws + 131072);
        unsigned short* act= (unsigned short*)(ws + 2228224);
        float* partials    = (float*)(ws + 39976960);

        cvt_x_kernel<<<1024, 256, 0, stream>>>(x, xb);
        routing_kernel<<<1024, 64, 0, stream>>>(x, gate_w, e_bias, combine);
        gateup_kernel<<<dim3(8, 144), 256, 0, stream>>>(xb, w_gate, w_up, ws_gate, ws_up, combine, act);
        down_kernel<<<dim3(8, 8, 4), 256, 0, stream>>>(act, w_down, ws_down, partials);
        reduce_kernel<<<1024, 256, 0, stream>>>(partials, out);
    }
}

// Round 4
// 435.761 us; speedup vs baseline: 1.4221x; 1.1483x over previous
//
#include <hip/hip_runtime.h>
#include <cstdint>
#include <cmath>

#define T_TOK 1024
#define H_DIM 1024
#define E_NUM 32
#define I_DIM 512
#define IS_DIM 2048
#define NCOL_R 16384
#define NCOL_T 18432
#define SCALE_F 2.5f
#define MAXTILES 96

typedef __bf16 bf16x8 __attribute__((ext_vector_type(8)));
typedef float f32x4 __attribute__((ext_vector_type(4)));

typedef __attribute__((address_space(3))) unsigned int lds_u32_t;
typedef __attribute__((address_space(1))) const unsigned int glb_u32_t;

__device__ __forceinline__ unsigned short f2b(float f) {
    union { float f; uint32_t u; } v; v.f = f;
    return (unsigned short)((v.u + 0x7FFFu + ((v.u >> 16) & 1u)) >> 16);
}

__device__ __forceinline__ void gll16(const unsigned short* g, unsigned short* l) {
    __builtin_amdgcn_global_load_lds((glb_u32_t*)g, (lds_u32_t*)l, 16, 0, 0);
}

// ---------------- X fp32 -> bf16 ----------------
__global__ void cvt_x_kernel(const float* __restrict__ x, unsigned short* __restrict__ xb) {
    int i = blockIdx.x * 256 + threadIdx.x;
    float4 v = reinterpret_cast<const float4*>(x)[i];
    uint2 o;
    o.x = (uint32_t)f2b(v.x) | ((uint32_t)f2b(v.y) << 16);
    o.y = (uint32_t)f2b(v.z) | ((uint32_t)f2b(v.w) << 16);
    reinterpret_cast<uint2*>(xb)[i] = o;
}

// ---------------- weight fp32 [R][C] -> bf16 transposed dst[c][r] ----------------
__global__ __launch_bounds__(256)
void tcvt_kernel(const float* __restrict__ src, unsigned short* __restrict__ dst,
                 int C, int DS, size_t src_batch, size_t dst_batch, size_t dst_base) {
    int b = blockIdx.z;
    int r0 = blockIdx.x * 64, c0 = blockIdx.y * 64;
    const float* s = src + (size_t)b * src_batch;
    __shared__ float tile[64][68];
    int t = threadIdx.x;
    int lr = t >> 4, lc4 = (t & 15) * 4;
#pragma unroll
    for (int p = 0; p < 4; p++) {
        float4 v = *reinterpret_cast<const float4*>(s + (size_t)(r0 + lr + p * 16) * C + c0 + lc4);
        *reinterpret_cast<float4*>(&tile[lr + p * 16][lc4]) = v;
    }
    __syncthreads();
    int oc = t >> 2, orr = (t & 3) * 16;
    uint32_t o[8];
#pragma unroll
    for (int j = 0; j < 8; j++)
        o[j] = (uint32_t)f2b(tile[orr + 2 * j][oc]) | ((uint32_t)f2b(tile[orr + 2 * j + 1][oc]) << 16);
    unsigned short* dp = dst + dst_base + (size_t)b * dst_batch + (size_t)(c0 + oc) * DS + r0 + orr;
    uint4 u0; u0.x = o[0]; u0.y = o[1]; u0.z = o[2]; u0.w = o[3];
    uint4 u1; u1.x = o[4]; u1.y = o[5]; u1.z = o[6]; u1.w = o[7];
    *reinterpret_cast<uint4*>(dp) = u0;
    *reinterpret_cast<uint4*>(dp + 8) = u1;
}

// ---------------- routing (+ top-8 ids) ----------------
__global__ void routing_kernel(const float* __restrict__ x,
                               const float* __restrict__ gate_w,
                               const float* __restrict__ e_bias,
                               float* __restrict__ combine,
                               int* __restrict__ topk) {
    int t = blockIdx.x;
    int l = threadIdx.x;   // 64 threads = 1 wave
    float xv[16];
#pragma unroll
    for (int i = 0; i < 16; i++) xv[i] = x[t * H_DIM + i * 64 + l];
    __shared__ float slog[E_NUM];
    for (int e = 0; e < E_NUM; e++) {
        const float* w = gate_w + e * H_DIM;
        float s = 0.f;
#pragma unroll
        for (int i = 0; i < 16; i++) s += xv[i] * w[i * 64 + l];
#pragma unroll
        for (int off = 32; off > 0; off >>= 1) s += __shfl_down(s, off);
        if (l == 0) slog[e] = s;
    }
    __syncthreads();
    if (l == 0) {
        float scores[E_NUM], swb[E_NUM];
        for (int e = 0; e < E_NUM; e++) {
            float sg = 1.f / (1.f + expf(-slog[e]));
            scores[e] = sg;
            swb[e] = sg + e_bias[e];
        }
        float gs[8];
        for (int g = 0; g < 8; g++) {
            float a0 = swb[4*g], a1 = swb[4*g+1], a2 = swb[4*g+2], a3 = swb[4*g+3];
            float hi01 = fmaxf(a0,a1), lo01 = fminf(a0,a1);
            float hi23 = fmaxf(a2,a3), lo23 = fminf(a2,a3);
            float m1 = fmaxf(hi01, hi23);
            float m2 = fmaxf(fminf(hi01, hi23), fmaxf(lo01, lo23));
            gs[g] = m1 + m2;
        }
        bool gsel[8];
        for (int g = 0; g < 8; g++) gsel[g] = false;
        for (int it = 0; it < 4; it++) {
            int bi = 0; float bv = -1e30f;
            for (int g = 0; g < 8; g++) if (!gsel[g] && gs[g] > bv) { bv = gs[g]; bi = g; }
            gsel[bi] = true;
        }
        float cand[E_NUM];
        for (int e = 0; e < E_NUM; e++) cand[e] = gsel[e >> 2] ? swb[e] : 0.0f;
        bool esel[E_NUM];
        for (int e = 0; e < E_NUM; e++) esel[e] = false;
        for (int it = 0; it < 8; it++) {
            int bi = 0; float bv = -1e30f;
            for (int e = 0; e < E_NUM; e++) if (!esel[e] && cand[e] > bv) { bv = cand[e]; bi = e; }
            esel[bi] = true;
            topk[t * 8 + it] = bi;
        }
        float ssum = 0.f;
        for (int e = 0; e < E_NUM; e++) if (esel[e]) ssum += scores[e];
        float inv = SCALE_F / (ssum + 1e-20f);
        for (int e = 0; e < E_NUM; e++)
            combine[t * E_NUM + e] = esel[e] ? scores[e] * inv : 0.0f;
    }
}

// ---------------- build expert segments (single block, 1024 threads) ----------------
// meta[0] = ntiles; meta[1+i] = expert of tile i. pair_token[MAXTILES*128], slot_of[T*8].
__global__ __launch_bounds__(1024)
void listbuild_kernel(const int* __restrict__ topk, int* __restrict__ meta,
                      int* __restrict__ pair_token, int* __restrict__ slot_of) {
    __shared__ int cnt[E_NUM], start[E_NUM], fill[E_NUM];
    int t = threadIdx.x;
    if (t < E_NUM) cnt[t] = 0;
    __syncthreads();
    int ids[8];
#pragma unroll
    for (int r = 0; r < 8; r++) {
        ids[r] = topk[t * 8 + r];
        atomicAdd(&cnt[ids[r]], 1);
    }
    __syncthreads();
    if (t == 0) {
        int acc = 0;
        for (int e = 0; e < E_NUM; e++) {
            int nt = (cnt[e] + 127) >> 7;
            start[e] = acc * 128;
            fill[e] = 0;
            for (int j = 0; j < nt; j++) meta[1 + acc + j] = e;
            acc += nt;
        }
        meta[0] = acc;
    }
    __syncthreads();
    for (int i = t; i < MAXTILES * 128; i += 1024) pair_token[i] = 0;
    __syncthreads();
#pragma unroll
    for (int r = 0; r < 8; r++) {
        int e = ids[r];
        int s = start[e] + atomicAdd(&fill[e], 1);
        pair_token[s] = t;
        slot_of[t * 8 + r] = s;
    }
}

// ---------------- sparse routed gate/up: act_s[slot][512] ----------------
__global__ __launch_bounds__(256, 2)
void gateup_s(const unsigned short* __restrict__ xb,
              const unsigned short* __restrict__ BG,   // [e*512+i][h]
              const unsigned short* __restrict__ BU,
              const float* __restrict__ combine,
              const int* __restrict__ pair_token,
              const int* __restrict__ meta,
              unsigned short* __restrict__ act_s) {
    int tile = blockIdx.x;
    if (tile >= meta[0]) return;
    int e = meta[1 + tile];
    int ci0 = blockIdx.y * 128;          // within I=512
    int brow0 = e * I_DIM + ci0;
    int slot0 = tile * 128;
    __shared__ __align__(16) unsigned short lA[128*32];
    __shared__ __align__(16) unsigned short lBg[128*32];
    __shared__ __align__(16) unsigned short lBu[128*32];
    int tid = threadIdx.x, lane = tid & 63, w = tid >> 6;
    int wr = w >> 1, wc = w & 1;
    f32x4 accg[4][4], accu[4][4];
#pragma unroll
    for (int i = 0; i < 4; i++)
#pragma unroll
        for (int j = 0; j < 4; j++)
#pragma unroll
            for (int r = 0; r < 4; r++) { accg[i][j][r] = 0.f; accu[i][j][r] = 0.f; }

    int srow = w * 32 + (lane >> 2);
    int schunk = (lane & 3) * 8;
    int tok0 = pair_token[slot0 + srow];
    int tok1 = pair_token[slot0 + srow + 16];
    const unsigned short* gA0 = xb + (size_t)tok0 * H_DIM + schunk;
    const unsigned short* gA1 = xb + (size_t)tok1 * H_DIM + schunk;
    const unsigned short* gG0 = BG + (size_t)(brow0 + srow) * H_DIM + schunk;
    const unsigned short* gU0 = BU + (size_t)(brow0 + srow) * H_DIM + schunk;
    unsigned short* lA0 = &lA[(w * 32) * 32];
    unsigned short* lG0 = &lBg[(w * 32) * 32];
    unsigned short* lU0 = &lBu[(w * 32) * 32];

    for (int kk = 0; kk < H_DIM / 32; kk++) {
        int k0 = kk * 32;
        __syncthreads();
        gll16(gA0 + k0, lA0);
        gll16(gA1 + k0, lA0 + 16 * 32);
        gll16(gG0 + k0, lG0);
        gll16(gG0 + 16 * H_DIM + k0, lG0 + 16 * 32);
        gll16(gU0 + k0, lU0);
        gll16(gU0 + 16 * H_DIM + k0, lU0 + 16 * 32);
        __syncthreads();
        bf16x8 af[4], bgf[4], buf2[4];
#pragma unroll
        for (int mi = 0; mi < 4; mi++)
            af[mi] = *reinterpret_cast<const bf16x8*>(&lA[(wr*64 + mi*16 + (lane & 15))*32 + (lane >> 4)*8]);
#pragma unroll
        for (int ni = 0; ni < 4; ni++) {
            int nn = (wc*64 + ni*16 + (lane & 15))*32 + (lane >> 4)*8;
            bgf[ni]  = *reinterpret_cast<const bf16x8*>(&lBg[nn]);
            buf2[ni] = *reinterpret_cast<const bf16x8*>(&lBu[nn]);
        }
#pragma unroll
        for (int mi = 0; mi < 4; mi++)
#pragma unroll
            for (int ni = 0; ni < 4; ni++) {
                accg[mi][ni] = __builtin_amdgcn_mfma_f32_16x16x32_bf16(af[mi], bgf[ni],  accg[mi][ni], 0, 0, 0);
                accu[mi][ni] = __builtin_amdgcn_mfma_f32_16x16x32_bf16(af[mi], buf2[ni], accu[mi][ni], 0, 0, 0);
            }
    }
    int q = lane >> 4, cl = lane & 15;
#pragma unroll
    for (int mi = 0; mi < 4; mi++) {
#pragma unroll
        for (int r = 0; r < 4; r++) {
            int row = wr*64 + mi*16 + q*4 + r;
            int token = pair_token[slot0 + row];
            float s = combine[token * E_NUM + e];
#pragma unroll
            for (int ni = 0; ni < 4; ni++) {
                float g = accg[mi][ni][r], u = accu[mi][ni][r];
                float a = g / (1.f + expf(-g)) * u * s;
                act_s[(size_t)(slot0 + row) * I_DIM + ci0 + wc*64 + ni*16 + cl] = f2b(a);
            }
        }
    }
}

// ---------------- shared expert gate/up: act_sh[t][2048] ----------------
__global__ __launch_bounds__(256, 2)
void shared_gateup(const unsigned short* __restrict__ xb,
                   const unsigned short* __restrict__ SG,   // [is][h]
                   const unsigned short* __restrict__ SU,
                   unsigned short* __restrict__ act_sh) {
    int row0 = blockIdx.x * 128, c0 = blockIdx.y * 128;
    __shared__ __align__(16) unsigned short lA[128*32];
    __shared__ __align__(16) unsigned short lBg[128*32];
    __shared__ __align__(16) unsigned short lBu[128*32];
    int tid = threadIdx.x, lane = tid & 63, w = tid >> 6;
    int wr = w >> 1, wc = w & 1;
    f32x4 accg[4][4], accu[4][4];
#pragma unroll
    for (int i = 0; i < 4; i++)
#pragma unroll
        for (int j = 0; j < 4; j++)
#pragma unroll
            for (int r = 0; r < 4; r++) { accg[i][j][r] = 0.f; accu[i][j][r] = 0.f; }

    int srow = w * 32 + (lane >> 2);
    int schunk = (lane & 3) * 8;
    const unsigned short* gA0 = xb + (size_t)(row0 + srow) * H_DIM + schunk;
    const unsigned short* gG0 = SG + (size_t)(c0 + srow) * H_DIM + schunk;
    const unsigned short* gU0 = SU + (size_t)(c0 + srow) * H_DIM + schunk;
    unsigned short* lA0 = &lA[(w * 32) * 32];
    unsigned short* lG0 = &lBg[(w * 32) * 32];
    unsigned short* lU0 = &lBu[(w * 32) * 32];

    for (int kk = 0; kk < H_DIM / 32; kk++) {
        int k0 = kk * 32;
        __syncthreads();
        gll16(gA0 + k0, lA0);
        gll16(gA0 + 16 * H_DIM + k0, lA0 + 16 * 32);
        gll16(gG0 + k0, lG0);
        gll16(gG0 + 16 * H_DIM + k0, lG0 + 16 * 32);
        gll16(gU0 + k0, lU0);
        gll16(gU0 + 16 * H_DIM + k0, lU0 + 16 * 32);
        __syncthreads();
        bf16x8 af[4], bgf[4], buf2[4];
#pragma unroll
        for (int mi = 0; mi < 4; mi++)
            af[mi] = *reinterpret_cast<const bf16x8*>(&lA[(wr*64 + mi*16 + (lane & 15))*32 + (lane >> 4)*8]);
#pragma unroll
        for (int ni = 0; ni < 4; ni++) {
            int nn = (wc*64 + ni*16 + (lane & 15))*32 + (lane >> 4)*8;
            bgf[ni]  = *reinterpret_cast<const bf16x8*>(&lBg[nn]);
            buf2[ni] = *reinterpret_cast<const bf16x8*>(&lBu[nn]);
        }
#pragma unroll
        for (int mi = 0; mi < 4; mi++)
#pragma unroll
            for (int ni = 0; ni < 4; ni++) {
                accg[mi][ni] = __builtin_amdgcn_mfma_f32_16x16x32_bf16(af[mi], bgf[ni],  accg[mi][ni], 0, 0, 0);
                accu[mi][ni] = __builtin_amdgcn_mfma_f32_16x16x32_bf16(af[mi], buf2[ni], accu[mi][ni], 0, 0, 0);
            }
    }
    int q = lane >> 4, cl = lane & 15;
#pragma unroll
    for (int mi = 0; mi < 4; mi++) {
#pragma unroll
        for (int ni = 0; ni < 4; ni++) {
            int col = c0 + wc*64 + ni*16 + cl;
#pragma unroll
            for (int r = 0; r < 4; r++) {
                int row = row0 + wr*64 + mi*16 + q*4 + r;
                float g = accg[mi][ni][r], u = accu[mi][ni][r];
                float a = g / (1.f + expf(-g)) * u;
                act_sh[(size_t)row * IS_DIM + col] = f2b(a);
            }
        }
    }
}

// ---------------- sparse down: pairpart[slot][1024] = act_s @ BDs_e^T ----------------
__global__ __launch_bounds__(256, 2)
void down_s(const unsigned short* __restrict__ act_s,
            const unsigned short* __restrict__ BDs,   // [e][h][i]
            const int* __restrict__ meta,
            float* __restrict__ pairpart) {
    int tile = blockIdx.x;
    if (tile >= meta[0]) return;
    int e = meta[1 + tile];
    int n0 = blockIdx.y * 128;
    int slot0 = tile * 128;
    __shared__ __align__(16) unsigned short lA[128*32];
    __shared__ __align__(16) unsigned short lB[128*32];
    int tid = threadIdx.x, lane = tid & 63, w = tid >> 6;
    int wr = w >> 1, wc = w & 1;
    f32x4 acc[4][4];
#pragma unroll
    for (int i = 0; i < 4; i++)
#pragma unroll
        for (int j = 0; j < 4; j++)
#pragma unroll
            for (int r = 0; r < 4; r++) acc[i][j][r] = 0.f;

    int srow = w * 32 + (lane >> 2);
    int schunk = (lane & 3) * 8;
    const unsigned short* gA0 = act_s + (size_t)(slot0 + srow) * I_DIM + schunk;
    const unsigned short* gB0 = BDs + (size_t)e * H_DIM * I_DIM + (size_t)(n0 + srow) * I_DIM + schunk;
    unsigned short* lA0 = &lA[(w * 32) * 32];
    unsigned short* lB0 = &lB[(w * 32) * 32];

    for (int kk = 0; kk < I_DIM / 32; kk++) {
        int k0 = kk * 32;
        __syncthreads();
        gll16(gA0 + k0, lA0);
        gll16(gA0 + 16 * I_DIM + k0, lA0 + 16 * 32);
        gll16(gB0 + k0, lB0);
        gll16(gB0 + 16 * I_DIM + k0, lB0 + 16 * 32);
        __syncthreads();
        bf16x8 af[4], bf[4];
#pragma unroll
        for (int mi = 0; mi < 4; mi++)
            af[mi] = *reinterpret_cast<const bf16x8*>(&lA[(wr*64 + mi*16 + (lane & 15))*32 + (lane >> 4)*8]);
#pragma unroll
        for (int ni = 0; ni < 4; ni++)
            bf[ni] = *reinterpret_cast<const bf16x8*>(&lB[(wc*64 + ni*16 + (lane & 15))*32 + (lane >> 4)*8]);
#pragma unroll
        for (int mi = 0; mi < 4; mi++)
#pragma unroll
            for (int ni = 0; ni < 4; ni++)
                acc[mi][ni] = __builtin_amdgcn_mfma_f32_16x16x32_bf16(af[mi], bf[ni], acc[mi][ni], 0, 0, 0);
    }
    int q = lane >> 4, cl = lane & 15;
#pragma unroll
    for (int mi = 0; mi < 4; mi++) {
#pragma unroll
        for (int ni = 0; ni < 4; ni++) {
            int col = n0 + wc*64 + ni*16 + cl;
#pragma unroll
            for (int r = 0; r < 4; r++) {
                int row = slot0 + wr*64 + mi*16 + q*4 + r;
                pairpart[(size_t)row * H_DIM + col] = acc[mi][ni][r];
            }
        }
    }
}

// ---------------- shared down: shpart[ks][t][1024], split-K=4 over IS ----------------
__global__ __launch_bounds__(256, 2)
void shared_down(const unsigned short* __restrict__ act_sh,
                 const unsigned short* __restrict__ BSD,   // [h][is]
                 float* __restrict__ shpart) {
    int mb = blockIdx.x, nb = blockIdx.y, ks = blockIdx.z;
    int row0 = mb * 128, n0 = nb * 128;
    __shared__ __align__(16) unsigned short lA[128*32];
    __shared__ __align__(16) unsigned short lB[128*32];
    int tid = threadIdx.x, lane = tid & 63, w = tid >> 6;
    int wr = w >> 1, wc = w & 1;
    f32x4 acc[4][4];
#pragma unroll
    for (int i = 0; i < 4; i++)
#pragma unroll
        for (int j = 0; j < 4; j++)
#pragma unroll
            for (int r = 0; r < 4; r++) acc[i][j][r] = 0.f;

    int srow = w * 32 + (lane >> 2);
    int schunk = (lane & 3) * 8;
    const unsigned short* gA0 = act_sh + (size_t)(row0 + srow) * IS_DIM + schunk;
    const unsigned short* gB0 = BSD + (size_t)(n0 + srow) * IS_DIM + schunk;
    unsigned short* lA0 = &lA[(w * 32) * 32];
    unsigned short* lB0 = &lB[(w * 32) * 32];

    for (int kk = 0; kk < 16; kk++) {
        int k0 = ks * 512 + kk * 32;
        __syncthreads();
        gll16(gA0 + k0, lA0);
        gll16(gA0 + 16 * IS_DIM + k0, lA0 + 16 * 32);
        gll16(gB0 + k0, lB0);
        gll16(gB0 + 16 * IS_DIM + k0, lB0 + 16 * 32);
        __syncthreads();
        bf16x8 af[4], bf[4];
#pragma unroll
        for (int mi = 0; mi < 4; mi++)
            af[mi] = *reinterpret_cast<const bf16x8*>(&lA[(wr*64 + mi*16 + (lane & 15))*32 + (lane >> 4)*8]);
#pragma unroll
        for (int ni = 0; ni < 4; ni++)
            bf[ni] = *reinterpret_cast<const bf16x8*>(&lB[(wc*64 + ni*16 + (lane & 15))*32 + (lane >> 4)*8]);
#pragma unroll
        for (int mi = 0; mi < 4; mi++)
#pragma unroll
            for (int ni = 0; ni < 4; ni++)
                acc[mi][ni] = __builtin_amdgcn_mfma_f32_16x16x32_bf16(af[mi], bf[ni], acc[mi][ni], 0, 0, 0);
    }
    float* pout = shpart + ((size_t)ks << 20);
    int q = lane >> 4, cl = lane & 15;
#pragma unroll
    for (int mi = 0; mi < 4; mi++) {
#pragma unroll
        for (int ni = 0; ni < 4; ni++) {
            int col = n0 + wc*64 + ni*16 + cl;
#pragma unroll
            for (int r = 0; r < 4; r++) {
                int row = row0 + wr*64 + mi*16 + q*4 + r;
                pout[(size_t)row * H_DIM + col] = acc[mi][ni][r];
            }
        }
    }
}

// ---------------- final combine: out = sum_r pairpart[slot_of] + sum_ks shpart ----------------
__global__ void final_combine(const float* __restrict__ pairpart,
                              const float* __restrict__ shpart,
                              const int* __restrict__ slot_of,
                              float* __restrict__ out) {
    int t = blockIdx.x;
    int h = threadIdx.x * 4;
    float4 o = reinterpret_cast<const float4*>(shpart + (size_t)t * H_DIM + h)[0];
#pragma unroll
    for (int ks = 1; ks < 4; ks++) {
        float4 v = reinterpret_cast<const float4*>(shpart + ((size_t)ks << 20) + (size_t)t * H_DIM + h)[0];
        o.x += v.x; o.y += v.y; o.z += v.z; o.w += v.w;
    }
#pragma unroll
    for (int r = 0; r < 8; r++) {
        int s = slot_of[t * 8 + r];
        float4 v = reinterpret_cast<const float4*>(pairpart + (size_t)s * H_DIM + h)[0];
        o.x += v.x; o.y += v.y; o.z += v.z; o.w += v.w;
    }
    reinterpret_cast<float4*>(out + (size_t)t * H_DIM + h)[0] = o;
}

// ================= FALLBACK PATH (round-1 kernels, small ws) =================

__global__ __launch_bounds__(256, 2)
void gateup_kernel(const unsigned short* __restrict__ xb,
                   const float* __restrict__ w_gate,
                   const float* __restrict__ w_up,
                   const float* __restrict__ ws_gate,
                   const float* __restrict__ ws_up,
                   const float* __restrict__ combine,
                   unsigned short* __restrict__ act) {
    int mb = blockIdx.x, cb = blockIdx.y;
    int row0 = mb * 128, c0 = cb * 128;
    const float *bg, *bu;
    int bstride, eidx;
    if (c0 < NCOL_R) {
        int e = c0 >> 9, ci = c0 & 511;
        bg = w_gate + (size_t)e * H_DIM * I_DIM + ci;
        bu = w_up   + (size_t)e * H_DIM * I_DIM + ci;
        bstride = I_DIM; eidx = e;
    } else {
        int ci = c0 - NCOL_R;
        bg = ws_gate + ci; bu = ws_up + ci;
        bstride = IS_DIM; eidx = -1;
    }
    __shared__ __align__(16) unsigned short lA[128*32];
    __shared__ __align__(16) unsigned short lBg[128*32];
    __shared__ __align__(16) unsigned short lBu[128*32];
    int tid = threadIdx.x, lane = tid & 63, w = tid >> 6;
    int wr = w >> 1, wc = w & 1;
    f32x4 accg[4][4], accu[4][4];
#pragma unroll
    for (int i = 0; i < 4; i++)
#pragma unroll
        for (int j = 0; j < 4; j++)
#pragma unroll
            for (int r = 0; r < 4; r++) { accg[i][j][r] = 0.f; accu[i][j][r] = 0.f; }
    int ar = tid >> 2, ak = (tid & 3) * 8;
    int bn = tid & 127, bkg = (tid >> 7) * 16;
    for (int kk = 0; kk < H_DIM / 32; kk++) {
        int k0 = kk * 32;
        __syncthreads();
        *reinterpret_cast<uint4*>(&lA[ar*32 + ak]) =
            *reinterpret_cast<const uint4*>(xb + (size_t)(row0 + ar) * H_DIM + k0 + ak);
        *reinterpret_cast<uint4*>(&lA[(ar+64)*32 + ak]) =
            *reinterpret_cast<const uint4*>(xb + (size_t)(row0 + ar + 64) * H_DIM + k0 + ak);
#pragma unroll
        for (int p = 0; p < 4; p++) {
            int kb = bkg + p * 4;
            const float* pg = bg + (size_t)(k0 + kb) * bstride + bn;
            uint2 dg;
            dg.x = (uint32_t)f2b(pg[0])         | ((uint32_t)f2b(pg[bstride])   << 16);
            dg.y = (uint32_t)f2b(pg[2*bstride]) | ((uint32_t)f2b(pg[3*bstride]) << 16);
            *reinterpret_cast<uint2*>(&lBg[bn*32 + kb]) = dg;
            const float* pu = bu + (size_t)(k0 + kb) * bstride + bn;
            uint2 du;
            du.x = (uint32_t)f2b(pu[0])         | ((uint32_t)f2b(pu[bstride])   << 16);
            du.y = (uint32_t)f2b(pu[2*bstride]) | ((uint32_t)f2b(pu[3*bstride]) << 16);
            *reinterpret_cast<uint2*>(&lBu[bn*32 + kb]) = du;
        }
        __syncthreads();
        bf16x8 af[4], bgf[4], buf2[4];
#pragma unroll
        for (int mi = 0; mi < 4; mi++)
            af[mi] = *reinterpret_cast<const bf16x8*>(&lA[(wr*64 + mi*16 + (lane & 15))*32 + (lane >> 4)*8]);
#pragma unroll
        for (int ni = 0; ni < 4; ni++) {
            int nn = (wc*64 + ni*16 + (lane & 15))*32 + (lane >> 4)*8;
            bgf[ni]  = *reinterpret_cast<const bf16x8*>(&lBg[nn]);
            buf2[ni] = *reinterpret_cast<const bf16x8*>(&lBu[nn]);
        }
#pragma unroll
        for (int mi = 0; mi < 4; mi++)
#pragma unroll
            for (int ni = 0; ni < 4; ni++) {
                accg[mi][ni] = __builtin_amdgcn_mfma_f32_16x16x32_bf16(af[mi], bgf[ni],  accg[mi][ni], 0, 0, 0);
                accu[mi][ni] = __builtin_amdgcn_mfma_f32_16x16x32_bf16(af[mi], buf2[ni], accu[mi][ni], 0, 0, 0);
            }
    }
    int q = lane >> 4, cl = lane & 15;
#pragma unroll
    for (int mi = 0; mi < 4; mi++) {
#pragma unroll
        for (int ni = 0; ni < 4; ni++) {
            int colg = c0 + wc*64 + ni*16 + cl;
#pragma unroll
            for (int r = 0; r < 4; r++) {
                int row = row0 + wr*64 + mi*16 + q*4 + r;
                float g = accg[mi][ni][r], u = accu[mi][ni][r];
                float a = g / (1.f + expf(-g)) * u;
                float s = (eidx >= 0) ? combine[row * E_NUM + eidx] : 1.0f;
                act[(size_t)row * NCOL_T + colg] = f2b(a * s);
            }
        }
    }
}

__global__ __launch_bounds__(256, 2)
void down_kernel(const unsigned short* __restrict__ act,
                 const float* __restrict__ w_down,
                 const float* __restrict__ ws_down,
                 float* __restrict__ partials) {
    int mb = blockIdx.x, nb = blockIdx.y, ks = blockIdx.z;
    int row0 = mb * 128, n0 = nb * 128;
    __shared__ __align__(16) unsigned short lA[128*32];
    __shared__ __align__(16) unsigned short lB[128*32];
    int tid = threadIdx.x, lane = tid & 63, w = tid >> 6;
    int wr = w >> 1, wc = w & 1;
    f32x4 acc[4][4];
#pragma unroll
    for (int i = 0; i < 4; i++)
#pragma unroll
        for (int j = 0; j < 4; j++)
#pragma unroll
            for (int r = 0; r < 4; r++) acc[i][j][r] = 0.f;
    int ar = tid >> 2, ak = (tid & 3) * 8;
    int bn = tid & 127, bkg = (tid >> 7) * 16;
    for (int kk = 0; kk < 144; kk++) {
        int k0 = ks * 4608 + kk * 32;
        const float* bb = (k0 < NCOL_R) ? (w_down + (size_t)k0 * H_DIM)
                                        : (ws_down + (size_t)(k0 - NCOL_R) * H_DIM);
        __syncthreads();
        *reinterpret_cast<uint4*>(&lA[ar*32 + ak]) =
            *reinterpret_cast<const uint4*>(act + (size_t)(row0 + ar) * NCOL_T + k0 + ak);
        *reinterpret_cast<uint4*>(&lA[(ar+64)*32 + ak]) =
            *reinterpret_cast<const uint4*>(act + (size_t)(row0 + ar + 64) * NCOL_T + k0 + ak);
#pragma unroll
        for (int p = 0; p < 4; p++) {
            int kb = bkg + p * 4;
            const float* pb = bb + (size_t)kb * H_DIM + n0 + bn;
            uint2 d;
            d.x = (uint32_t)f2b(pb[0])       | ((uint32_t)f2b(pb[H_DIM])   << 16);
            d.y = (uint32_t)f2b(pb[2*H_DIM]) | ((uint32_t)f2b(pb[3*H_DIM]) << 16);
            *reinterpret_cast<uint2*>(&lB[bn*32 + kb]) = d;
        }
        __syncthreads();
        bf16x8 af[4], bf[4];
#pragma unroll
        for (int mi = 0; mi < 4; mi++)
            af[mi] = *reinterpret_cast<const bf16x8*>(&lA[(wr*64 + mi*16 + (lane & 15))*32 + (lane >> 4)*8]);
#pragma unroll
        for (int ni = 0; ni < 4; ni++)
            bf[ni] = *reinterpret_cast<const bf16x8*>(&lB[(wc*64 + ni*16 + (lane & 15))*32 + (lane >> 4)*8]);
#pragma unroll
        for (int mi = 0; mi < 4; mi++)
#pragma unroll
            for (int ni = 0; ni < 4; ni++)
                acc[mi][ni] = __builtin_amdgcn_mfma_f32_16x16x32_bf16(af[mi], bf[ni], acc[mi][ni], 0, 0, 0);
    }
    float* pout = partials + ((size_t)ks << 20);
    int q = lane >> 4, cl = lane & 15;
#pragma unroll
    for (int mi = 0; mi < 4; mi++) {
#pragma unroll
        for (int ni = 0; ni < 4; ni++) {
            int col = n0 + wc*64 + ni*16 + cl;
#pragma unroll
            for (int r = 0; r < 4; r++) {
                int row = row0 + wr*64 + mi*16 + q*4 + r;
                pout[(size_t)row * H_DIM + col] = acc[mi][ni][r];
            }
        }
    }
}

__global__ void reduce_kernel(const float* __restrict__ p, float* __restrict__ out) {
    int i = blockIdx.x * 256 + threadIdx.x;
    float4 a = reinterpret_cast<const float4*>(p)[i];
    float4 b = reinterpret_cast<const float4*>(p + (size_t)1048576)[i];
    float4 c = reinterpret_cast<const float4*>(p + (size_t)2097152)[i];
    float4 d = reinterpret_cast<const float4*>(p + (size_t)3145728)[i];
    float4 o;
    o.x = a.x + b.x + c.x + d.x;
    o.y = a.y + b.y + c.y + d.y;
    o.z = a.z + b.z + c.z + d.z;
    o.w = a.w + b.w + c.w + d.w;
    reinterpret_cast<float4*>(out)[i] = o;
}

extern "C" void kernel_launch(void* const* d_in, const int* in_sizes, int n_in,
                              void* d_out, int out_size, void* d_ws, size_t ws_size,
                              hipStream_t stream) {
    const float* x       = (const float*)d_in[0];
    const float* gate_w  = (const float*)d_in[1];
    const float* e_bias  = (const float*)d_in[2];
    const float* w_gate  = (const float*)d_in[3];
    const float* w_up    = (const float*)d_in[4];
    const float* w_down  = (const float*)d_in[5];
    const float* ws_gate = (const float*)d_in[6];
    const float* ws_up   = (const float*)d_in[7];
    const float* ws_down = (const float*)d_in[8];
    float* out = (float*)d_out;

    char* ws = (char*)d_ws;
    bool fast = ws_size >= 170000384ull;   // ws_size constant across calls -> capture-safe branch

    if (fast) {
        float* combine      = (float*)(ws);                       // 131072
        int*   topk         = (int*)(ws + 131072);                // 32768
        int*   meta         = (int*)(ws + 163840);                // 512
        int*   pair_token   = (int*)(ws + 164352);                // 49152
        int*   slot_of      = (int*)(ws + 213504);                // 32768
        unsigned short* xb  = (unsigned short*)(ws + 262144);     // 2 MB
        unsigned short* act_s  = (unsigned short*)(ws + 2359296);    // 12.6 MB
        unsigned short* act_sh = (unsigned short*)(ws + 14942208);   // 4 MB
        unsigned short* BG  = (unsigned short*)(ws + 19136512);      // 32 MB
        unsigned short* BU  = (unsigned short*)(ws + 52690944);      // 32 MB
        unsigned short* SG  = (unsigned short*)(ws + 86245376);      // 4 MB
        unsigned short* SU  = (unsigned short*)(ws + 90439680);      // 4 MB
        unsigned short* BDs = (unsigned short*)(ws + 94633984);      // 32 MB
        unsigned short* BSD = (unsigned short*)(ws + 128188416);     // 4 MB
        // partials alias dead BG/BU region (BG/BU only used by gateup_s / shared_gateup)
        float* pairpart     = (float*)(ws + 19136512);               // 50.33 MB
        float* shpart       = (float*)(ws + 69468160);               // 16 MB, ends 86245376

        cvt_x_kernel<<<1024, 256, 0, stream>>>(x, xb);
        routing_kernel<<<1024, 64, 0, stream>>>(x, gate_w, e_bias, combine, topk);
        listbuild_kernel<<<1, 1024, 0, stream>>>(topk, meta, pair_token, slot_of);
        // w_gate [32][1024h][512i] -> BG[e*512+i][h]
        tcvt_kernel<<<dim3(16, 8, 32), 256, 0, stream>>>(w_gate, BG, 512, 1024, 524288, 524288, 0);
        tcvt_kernel<<<dim3(16, 8, 32), 256, 0, stream>>>(w_up,   BU, 512, 1024, 524288, 524288, 0);
        // ws_gate [1024h][2048is] -> SG[is][h]
        tcvt_kernel<<<dim3(16, 32, 1), 256, 0, stream>>>(ws_gate, SG, 2048, 1024, 0, 0, 0);
        tcvt_kernel<<<dim3(16, 32, 1), 256, 0, stream>>>(ws_up,   SU, 2048, 1024, 0, 0, 0);
        // w_down [32][512i][1024h] -> BDs[e][h][i]
        tcvt_kernel<<<dim3(8, 16, 32), 256, 0, stream>>>(w_down, BDs, 1024, 512, 524288, 524288, 0);
        // ws_down [2048is][1024h] -> BSD[h][is]
        tcvt_kernel<<<dim3(32, 16, 1), 256, 0, stream>>>(ws_down, BSD, 1024, 2048, 0, 0, 0);

        gateup_s<<<dim3(MAXTILES, 4), 256, 0, stream>>>(xb, BG, BU, combine, pair_token, meta, act_s);
        shared_gateup<<<dim3(8, 16), 256, 0, stream>>>(xb, SG, SU, act_sh);
        down_s<<<dim3(MAXTILES, 8), 256, 0, stream>>>(act_s, BDs, meta, pairpart);
        shared_down<<<dim3(8, 8, 4), 256, 0, stream>>>(act_sh, BSD, shpart);
        final_combine<<<1024, 256, 0, stream>>>(pairpart, shpart, slot_of, out);
    } else {
        float* combine     = (float*)(ws);
        int*   topk        = (int*)(ws + 131072);
        unsigned short* xb = (unsigned short*)(ws + 262144);
        unsigned short* act= (unsigned short*)(ws + 2359296);
        float* partials    = (float*)(ws + 40108032);

        cvt_x_kernel<<<1024, 256, 0, stream>>>(x, xb);
        routing_kernel<<<1024, 64, 0, stream>>>(x, gate_w, e_bias, combine, topk);
        gateup_kernel<<<dim3(8, 144), 256, 0, stream>>>(xb, w_gate, w_up, ws_gate, ws_up, combine, act);
        down_kernel<<<dim3(8, 8, 4), 256, 0, stream>>>(act, w_down, ws_down, partials);
        reduce_kernel<<<1024, 256, 0, stream>>>(partials, out);
    }
}